// Round 4
// baseline (196.908 us; speedup 1.0000x reference)
//
#include <hip/hip_runtime.h>

typedef __attribute__((ext_vector_type(8))) short short8;
typedef __attribute__((ext_vector_type(16))) float f32x16;
typedef __attribute__((ext_vector_type(4))) unsigned short ushort4v;

#define BN_EPS 1e-5f
#define KOFF 27

static __device__ __forceinline__ unsigned short f2bf(float f) {
  unsigned int u = __float_as_uint(f);
  u += 0x7fffu + ((u >> 16) & 1u);
  return (unsigned short)(u >> 16);
}

static __device__ __forceinline__ float silu_f(float z) {
  return z / (1.f + __expf(-z));
}

// ---- time embedding MLP: tp = silu(t) @ Wt + bt; store (1+scale), shift
__global__ void time_mlp(const float* __restrict__ t, const float* __restrict__ Wt,
                         const float* __restrict__ bt,
                         float* __restrict__ scale_eff, float* __restrict__ shift) {
  int tid = blockIdx.x * blockDim.x + threadIdx.x; // 2048 = 16 batches * 128 out
  int bi = tid >> 7, co = tid & 127;
  float acc = bt[co];
  for (int e = 0; e < 256; ++e) {
    float tv = t[bi * 256 + e];
    acc += silu_f(tv) * Wt[e * 128 + co];
  }
  if (co < 64) scale_eff[bi * 64 + co] = 1.f + acc;
  else         shift[bi * 64 + (co - 64)] = acc;
}

// ---- pack W1 and W2 [k, ci, co] (f32) into bf16 MFMA B-fragment order (32x32x16).
// Fragment f = (k*4 + ks)*2 + cb : lane l elem j <- W[k][ks*16 + (l>>5)*8 + j][cb*32 + (l&31)]
__global__ void pack_w32(const float* __restrict__ W1, const float* __restrict__ W2,
                         unsigned short* __restrict__ Wp1, unsigned short* __restrict__ Wp2) {
  const int tot = KOFF * 4 * 2 * 64 * 8;
  int tid = blockIdx.x * blockDim.x + threadIdx.x;
  const float* W = W1;
  unsigned short* Wp = Wp1;
  if (tid >= tot) { tid -= tot; W = W2; Wp = Wp2; }
  if (tid >= tot) return;
  int j = tid & 7, lane = (tid >> 3) & 63, cb = (tid >> 9) & 1, ks = (tid >> 10) & 3, k = tid >> 12;
  int ci = ks * 16 + (lane >> 5) * 8 + j;
  int co = cb * 32 + (lane & 31);
  Wp[tid] = f2bf(W[(k * 64 + ci) * 64 + co]);
}

// ---- a1 = bf16(silu(bn1(x))), bn1 affine computed inline; tail threads zero row N
__global__ void bn_silu_k(const float* __restrict__ x, const float* __restrict__ g1,
                          const float* __restrict__ b1, const float* __restrict__ m1,
                          const float* __restrict__ v1, unsigned short* __restrict__ out,
                          int total) {
  int i = (blockIdx.x * blockDim.x + threadIdx.x) * 4;
  if (i >= total) {
    if (i < total + 64) *(ushort4v*)(out + i) = (ushort4v){0, 0, 0, 0};
    return;
  }
  float4 v = *(const float4*)(x + i);
  int c = i & 63;
  float4 g = *(const float4*)(g1 + c);
  float4 b = *(const float4*)(b1 + c);
  float4 m = *(const float4*)(m1 + c);
  float4 vv = *(const float4*)(v1 + c);
  ushort4v r;
  float sx = g.x * rsqrtf(vv.x + BN_EPS);
  float sy = g.y * rsqrtf(vv.y + BN_EPS);
  float sz = g.z * rsqrtf(vv.z + BN_EPS);
  float sw = g.w * rsqrtf(vv.w + BN_EPS);
  r.x = f2bf(silu_f((v.x - m.x) * sx + b.x));
  r.y = f2bf(silu_f((v.y - m.y) * sy + b.y));
  r.z = f2bf(silu_f((v.z - m.z) * sz + b.z));
  r.w = f2bf(silu_f((v.w - m.w) * sw + b.w));
  *(ushort4v*)(out + i) = r;
}

// ---- sparse conv: 4 waves/block, 32 nodes/wave (32x32x16 MFMA), 128 nodes/block.
// Branch-free k-loop: rows[k] = valid ? idx : N (row N is zeros in act).
// Pipeline discipline: CONSUME buffer (MF) before REFILL (GATH k+3).
// MODE 0: epilogue = +bias, FiLM, bn2+silu -> bf16 a2 (also zeroes a2 row N via block 0)
// MODE 1: epilogue = +bias + residual x -> f32 out
template <int MODE>
__global__ __launch_bounds__(256, 3) void conv_k(
    const unsigned short* __restrict__ act, const int* __restrict__ idx,
    const int* __restrict__ valid, const unsigned short* __restrict__ Wp,
    const float* __restrict__ bias,
    const float* __restrict__ scale_eff, const float* __restrict__ shift,
    const int* __restrict__ bidx,
    const float* __restrict__ g2, const float* __restrict__ b2,
    const float* __restrict__ m2, const float* __restrict__ v2,
    const float* __restrict__ xres,
    unsigned short* __restrict__ out_bf, float* __restrict__ out_f, int N) {
  if (MODE == 0 && blockIdx.x == 0 && threadIdx.x < 64) {
    out_bf[(size_t)N * 64 + threadIdx.x] = 0;  // zero row for conv2's invalid taps
  }
  const int lane = threadIdx.x & 63;
  const int wid = threadIdx.x >> 6;
  const int half = lane >> 5;     // 0/1
  const int r32 = lane & 31;
  const int n0w = blockIdx.x * 128 + wid * 32;
  const int nAc = min(n0w + r32, N - 1);   // clamped; OOB lanes compute garbage, never stored

  // preload all (valid, idx) -> safe gather rows
  int rows[KOFF];
#pragma unroll
  for (int k = 0; k < KOFF; ++k) {
    int v = valid[(size_t)k * N + nAc];
    int g = idx[(size_t)k * N + nAc];
    rows[k] = v ? g : N;
  }

  f32x16 acc0, acc1;
#pragma unroll
  for (int i = 0; i < 16; ++i) { acc0[i] = 0.f; acc1[i] = 0.f; }

  short8 A0[4], A1[4], A2[4];

#define GATH(AR, kk) do { \
    const short8* rp = (const short8*)(act + (size_t)rows[kk] * 64) + half; \
    AR[0] = rp[0]; AR[1] = rp[2]; AR[2] = rp[4]; AR[3] = rp[6]; \
  } while (0)

#define MF(AR, kk) do { \
    const short8* wb = (const short8*)Wp + (size_t)(kk) * 512 + lane; \
    acc0 = __builtin_amdgcn_mfma_f32_32x32x16_bf16(AR[0], wb[0 * 128 + 0],  acc0, 0, 0, 0); \
    acc1 = __builtin_amdgcn_mfma_f32_32x32x16_bf16(AR[0], wb[0 * 128 + 64], acc1, 0, 0, 0); \
    acc0 = __builtin_amdgcn_mfma_f32_32x32x16_bf16(AR[1], wb[1 * 128 + 0],  acc0, 0, 0, 0); \
    acc1 = __builtin_amdgcn_mfma_f32_32x32x16_bf16(AR[1], wb[1 * 128 + 64], acc1, 0, 0, 0); \
    acc0 = __builtin_amdgcn_mfma_f32_32x32x16_bf16(AR[2], wb[2 * 128 + 0],  acc0, 0, 0, 0); \
    acc1 = __builtin_amdgcn_mfma_f32_32x32x16_bf16(AR[2], wb[2 * 128 + 64], acc1, 0, 0, 0); \
    acc0 = __builtin_amdgcn_mfma_f32_32x32x16_bf16(AR[3], wb[3 * 128 + 0],  acc0, 0, 0, 0); \
    acc1 = __builtin_amdgcn_mfma_f32_32x32x16_bf16(AR[3], wb[3 * 128 + 64], acc1, 0, 0, 0); \
  } while (0)

  GATH(A0, 0);
  GATH(A1, 1);
  GATH(A2, 2);
#pragma unroll
  for (int k = 0; k < KOFF; ++k) {
    const int s = k % 3;
    if (s == 0) {
      MF(A0, k);
      if (k + 3 < KOFF) GATH(A0, k + 3);
    } else if (s == 1) {
      MF(A1, k);
      if (k + 3 < KOFF) GATH(A1, k + 3);
    } else {
      MF(A2, k);
      if (k + 3 < KOFF) GATH(A2, k + 3);
    }
  }
#undef GATH
#undef MF

  // D frag: col = cb*32 + (lane&31), row = (r&3) + 8*(r>>2) + 4*half
  if (MODE == 0) {
#pragma unroll
    for (int cb = 0; cb < 2; ++cb) {
      f32x16 a = cb ? acc1 : acc0;
      int c = cb * 32 + r32;
      float bb = bias[c];
      float s2v = g2[c] * rsqrtf(v2[c] + BN_EPS);
      float o2v = b2[c] - m2[c] * s2v;
#pragma unroll
      for (int r = 0; r < 16; ++r) {
        int row = (r & 3) + 8 * (r >> 2) + 4 * half;
        int n = n0w + row;
        if (n < N) {
          int bi = bidx[n];
          float h = a[r] + bb;
          h = scale_eff[bi * 64 + c] * h + shift[bi * 64 + c];
          float z = h * s2v + o2v;
          out_bf[(size_t)n * 64 + c] = f2bf(silu_f(z));
        }
      }
    }
  } else {
#pragma unroll
    for (int cb = 0; cb < 2; ++cb) {
      f32x16 a = cb ? acc1 : acc0;
      int c = cb * 32 + r32;
      float bb = bias[c];
#pragma unroll
      for (int r = 0; r < 16; ++r) {
        int row = (r & 3) + 8 * (r >> 2) + 4 * half;
        int n = n0w + row;
        if (n < N) {
          out_f[(size_t)n * 64 + c] = a[r] + bb + xres[(size_t)n * 64 + c];
        }
      }
    }
  }
}

extern "C" void kernel_launch(void* const* d_in, const int* in_sizes, int n_in,
                              void* d_out, int out_size, void* d_ws, size_t ws_size,
                              hipStream_t stream) {
  const float* x    = (const float*)d_in[0];
  const float* t    = (const float*)d_in[1];
  const int*   b    = (const int*)d_in[2];
  const int*   kidx = (const int*)d_in[3];
  const int*   kval = (const int*)d_in[4];
  const float* bn1g = (const float*)d_in[5];
  const float* bn1b = (const float*)d_in[6];
  const float* bn1m = (const float*)d_in[7];
  const float* bn1v = (const float*)d_in[8];
  const float* W1   = (const float*)d_in[9];
  const float* b1c  = (const float*)d_in[10];
  const float* bn2g = (const float*)d_in[11];
  const float* bn2b = (const float*)d_in[12];
  const float* bn2m = (const float*)d_in[13];
  const float* bn2v = (const float*)d_in[14];
  const float* W2   = (const float*)d_in[15];
  const float* b2c  = (const float*)d_in[16];
  const float* Wt   = (const float*)d_in[17];
  const float* bt   = (const float*)d_in[18];
  float* out = (float*)d_out;

  const int N = in_sizes[2];        // 100000
  const int total = N * 64;

  // workspace layout (bytes); act buffers have N+1 rows (row N = zeros)
  char* ws = (char*)d_ws;
  size_t actB = ((size_t)(N + 1) * 64 * 2 + 255) & ~(size_t)255;
  unsigned short* a1bf = (unsigned short*)ws;
  unsigned short* a2bf = (unsigned short*)(ws + actB);
  const size_t wpackB = (size_t)KOFF * 4 * 2 * 64 * 8 * 2;  // 221184 B
  unsigned short* W1p = (unsigned short*)(ws + 2 * actB);
  unsigned short* W2p = (unsigned short*)(ws + 2 * actB + wpackB);
  float* scale_eff = (float*)(ws + 2 * actB + 2 * wpackB);
  float* shiftp    = scale_eff + 16 * 64;

  time_mlp<<<8, 256, 0, stream>>>(t, Wt, bt, scale_eff, shiftp);
  const int wtot = KOFF * 4 * 2 * 64 * 8;
  pack_w32<<<(2 * wtot + 255) / 256, 256, 0, stream>>>(W1, W2, W1p, W2p);
  bn_silu_k<<<(total / 4 + 16 + 255) / 256, 256, 0, stream>>>(x, bn1g, bn1b, bn1m,
                                                              bn1v, a1bf, total);

  int nblk = (N + 127) / 128;
  conv_k<0><<<nblk, 256, 0, stream>>>(a1bf, kidx, kval, W1p, b1c, scale_eff,
                                      shiftp, b, bn2g, bn2b, bn2m, bn2v,
                                      nullptr, a2bf, nullptr, N);
  conv_k<1><<<nblk, 256, 0, stream>>>(a2bf, kidx, kval, W2p, b2c, nullptr, nullptr,
                                      nullptr, nullptr, nullptr, nullptr, nullptr,
                                      x, nullptr, out, N);
}

// Round 6
// 143.962 us; speedup vs baseline: 1.3678x; 1.3678x over previous
//
#include <hip/hip_runtime.h>

typedef __attribute__((ext_vector_type(8))) short short8;
typedef __attribute__((ext_vector_type(16))) float f32x16;
typedef __attribute__((ext_vector_type(4))) unsigned short ushort4v;

#define BN_EPS 1e-5f
#define KOFF 27

static __device__ __forceinline__ unsigned short f2bf(float f) {
  unsigned int u = __float_as_uint(f);
  u += 0x7fffu + ((u >> 16) & 1u);
  return (unsigned short)(u >> 16);
}

static __device__ __forceinline__ float silu_f(float z) {
  return z / (1.f + __expf(-z));
}

static __device__ __forceinline__ void gload_lds16(const void* g, void* l) {
  __builtin_amdgcn_global_load_lds(
      (const __attribute__((address_space(1))) unsigned int*)g,
      (__attribute__((address_space(3))) unsigned int*)l, 16, 0, 0);
}

// ---- time embedding MLP: tp = silu(t) @ Wt + bt; store (1+scale), shift
__global__ void time_mlp(const float* __restrict__ t, const float* __restrict__ Wt,
                         const float* __restrict__ bt,
                         float* __restrict__ scale_eff, float* __restrict__ shift) {
  int tid = blockIdx.x * blockDim.x + threadIdx.x; // 2048 = 16 batches * 128 out
  int bi = tid >> 7, co = tid & 127;
  float acc = bt[co];
  for (int e = 0; e < 256; ++e) {
    float tv = t[bi * 256 + e];
    acc += silu_f(tv) * Wt[e * 128 + co];
  }
  if (co < 64) scale_eff[bi * 64 + co] = 1.f + acc;
  else         shift[bi * 64 + (co - 64)] = acc;
}

// ---- pack W1 and W2 [k, ci, co] (f32) into bf16 MFMA B-fragment order (32x32x16).
// Fragment f = k*8 + ks*2 + cb : lane l elem j <- W[k][ks*16 + (l>>5)*8 + j][cb*32 + (l&31)]
__global__ void pack_w32(const float* __restrict__ W1, const float* __restrict__ W2,
                         unsigned short* __restrict__ Wp1, unsigned short* __restrict__ Wp2) {
  const int tot = KOFF * 4 * 2 * 64 * 8;
  int tid = blockIdx.x * blockDim.x + threadIdx.x;
  const float* W = W1;
  unsigned short* Wp = Wp1;
  if (tid >= tot) { tid -= tot; W = W2; Wp = Wp2; }
  if (tid >= tot) return;
  int j = tid & 7, lane = (tid >> 3) & 63, cb = (tid >> 9) & 1, ks = (tid >> 10) & 3, k = tid >> 12;
  int ci = ks * 16 + (lane >> 5) * 8 + j;
  int co = cb * 32 + (lane & 31);
  Wp[tid] = f2bf(W[(k * 64 + ci) * 64 + co]);
}

// ---- a1 = bf16(silu(bn1(x))), bn1 affine computed inline; tail threads zero row N
__global__ void bn_silu_k(const float* __restrict__ x, const float* __restrict__ g1,
                          const float* __restrict__ b1, const float* __restrict__ m1,
                          const float* __restrict__ v1, unsigned short* __restrict__ out,
                          int total) {
  int i = (blockIdx.x * blockDim.x + threadIdx.x) * 4;
  if (i >= total) {
    if (i < total + 64) *(ushort4v*)(out + i) = (ushort4v){0, 0, 0, 0};
    return;
  }
  float4 v = *(const float4*)(x + i);
  int c = i & 63;
  float4 g = *(const float4*)(g1 + c);
  float4 b = *(const float4*)(b1 + c);
  float4 m = *(const float4*)(m1 + c);
  float4 vv = *(const float4*)(v1 + c);
  ushort4v r;
  float sx = g.x * rsqrtf(vv.x + BN_EPS);
  float sy = g.y * rsqrtf(vv.y + BN_EPS);
  float sz = g.z * rsqrtf(vv.z + BN_EPS);
  float sw = g.w * rsqrtf(vv.w + BN_EPS);
  r.x = f2bf(silu_f((v.x - m.x) * sx + b.x));
  r.y = f2bf(silu_f((v.y - m.y) * sy + b.y));
  r.z = f2bf(silu_f((v.z - m.z) * sz + b.z));
  r.w = f2bf(silu_f((v.w - m.w) * sw + b.w));
  *(ushort4v*)(out + i) = r;
}

// ---- sparse conv with LDS-staged gather.
// Block = 256 threads / 4 waves / 128 nodes. Per k-offset: the block's 128 gathered
// rows (128 x 64 bf16 = 16 KB) are staged cooperatively into LDS via global_load_lds
// (8 lanes x 16 B per row -> full-line coalesced), double-buffered (one barrier/k).
// 16B XOR swizzle (chunk ^= row&7) applied on the GLOBAL SRC side (LDS dest linear,
// rule #21) makes ds_read_b128 fragment reads bank-conflict-free.
// Tap-parity discipline: rgA holds EVEN taps, rgB holds ODD taps.
//   iter k: STAGE(tap k+1 from rg[(k+1)&1]) ; LDVG(tap k+2 into rg[k&1]) ; COMPUTE(tap k)
// Wave w: rows RH*64..+63 (RH=w>>1, 2 sub-tiles of 32), cols cb*32..+31 (cb=w&1).
// MODE 0: epilogue = +bias, FiLM, bn2+silu -> bf16 a2 (block 0 zeroes a2 row N)
// MODE 1: epilogue = +bias + residual x -> f32 out
template <int MODE>
__global__ __launch_bounds__(256, 3) void conv_k(
    const unsigned short* __restrict__ act, const int* __restrict__ idx,
    const int* __restrict__ valid, const unsigned short* __restrict__ Wp,
    const float* __restrict__ bias,
    const float* __restrict__ scale_eff, const float* __restrict__ shift,
    const int* __restrict__ bidx,
    const float* __restrict__ g2, const float* __restrict__ b2,
    const float* __restrict__ m2, const float* __restrict__ v2,
    const float* __restrict__ xres,
    unsigned short* __restrict__ out_bf, float* __restrict__ out_f, int N) {
  __shared__ unsigned short lds[2][128 * 64];

  if (MODE == 0 && blockIdx.x == 0 && threadIdx.x < 64) {
    out_bf[(size_t)N * 64 + threadIdx.x] = 0;  // zero row for conv2's invalid taps
  }
  const int tid = threadIdx.x;
  const int lane = tid & 63;
  const int wid = tid >> 6;
  const int half = lane >> 5;   // 0/1
  const int r32 = lane & 31;
  const int n0 = blockIdx.x * 128;

  // staging role: lane stages rows rowL = wid*32 + i*8 + (lane>>3), phys chunk lane&7
  const int rowL0 = wid * 32 + (lane >> 3);
  const int q0 = lane & 7;
  // compute role
  const int RH = wid >> 1;
  const int cb = wid & 1;

  f32x16 acc0, acc1;
#pragma unroll
  for (int i = 0; i < 16; ++i) { acc0[i] = 0.f; acc1[i] = 0.f; }

  int rgA[4], rgB[4];   // rgA: even taps, rgB: odd taps

#define LDVG(kk, rg) do { \
    _Pragma("unroll") \
    for (int i = 0; i < 4; ++i) { \
      int node = min(n0 + rowL0 + i * 8, N - 1); \
      int v = valid[(size_t)(kk) * N + node]; \
      int g = idx[(size_t)(kk) * N + node]; \
      rg[i] = v ? g : N; \
    } } while (0)

  // LDS dest base is wave-uniform; HW adds lane*16. Lane's 16B lands at
  // row (wid*32+i*8+(lane>>3)), phys chunk (lane&7) -> row-major linear.
  // Source chunk pre-swizzled: srcq = (lane&7) ^ (row&7) = q0 ^ (lane>>3).
#define STAGE(buf, rg) do { \
    _Pragma("unroll") \
    for (int i = 0; i < 4; ++i) { \
      int srcq = q0 ^ (lane >> 3); \
      const unsigned short* src = act + (size_t)rg[i] * 64 + srcq * 8; \
      unsigned short* dst = &lds[buf][(wid * 32 + i * 8) * 64]; \
      gload_lds16(src, dst); \
    } } while (0)

  // fragment reads: logical chunk q = ks*2 + half of row R; phys p = q ^ (R&7); R&7 == r32&7
#define COMPUTE(buf, kk) do { \
    short8 wf[4]; \
    _Pragma("unroll") \
    for (int ks = 0; ks < 4; ++ks) \
      wf[ks] = ((const short8*)Wp)[((size_t)(kk) * 8 + ks * 2 + cb) * 64 + lane]; \
    _Pragma("unroll") \
    for (int ks = 0; ks < 4; ++ks) { \
      int p = (ks * 2 + half) ^ (r32 & 7); \
      short8 a0v = *(const short8*)(&lds[buf][(RH * 64 + r32) * 64] + p * 8); \
      short8 a1v = *(const short8*)(&lds[buf][(RH * 64 + 32 + r32) * 64] + p * 8); \
      acc0 = __builtin_amdgcn_mfma_f32_32x32x16_bf16(a0v, wf[ks], acc0, 0, 0, 0); \
      acc1 = __builtin_amdgcn_mfma_f32_32x32x16_bf16(a1v, wf[ks], acc1, 0, 0, 0); \
    } } while (0)

  LDVG(0, rgA);        // tap 0 (even) -> rgA
  STAGE(0, rgA);       // buf0 <- tap 0
  LDVG(1, rgB);        // tap 1 (odd) -> rgB
  __syncthreads();     // implicit vmcnt(0): buf0 staged

#pragma unroll
  for (int k = 0; k < KOFF; ++k) {
    // STAGE tap k+1 (parity (k+1)&1) into buf (k+1)&1
    if (k + 1 < KOFF) {
      if ((k + 1) & 1) STAGE((k + 1) & 1, rgB);
      else             STAGE((k + 1) & 1, rgA);
    }
    // LDVG tap k+2 (parity k&1) into its set (consumed by STAGE at iter k-1)
    if (k + 2 < KOFF) {
      if (k & 1) LDVG(k + 2, rgB);
      else       LDVG(k + 2, rgA);
    }
    COMPUTE(k & 1, k);
    __syncthreads();  // implicit vmcnt(0)+lgkmcnt(0): stage k+1 done, reads of buf k done
  }
#undef LDVG
#undef STAGE
#undef COMPUTE

  // D frag: col = cb*32 + r32, row-in-subtile = (r&3) + 8*(r>>2) + 4*half
  if (MODE == 0) {
#pragma unroll
    for (int s = 0; s < 2; ++s) {
      f32x16 a = s ? acc1 : acc0;
      const int c = cb * 32 + r32;
      float bb = bias[c];
      float s2v = g2[c] * rsqrtf(v2[c] + BN_EPS);
      float o2v = b2[c] - m2[c] * s2v;
#pragma unroll
      for (int r = 0; r < 16; ++r) {
        int rowD = (r & 3) + 8 * (r >> 2) + 4 * half;
        int n = n0 + RH * 64 + s * 32 + rowD;
        if (n < N) {
          int bi = bidx[n];
          float h = a[r] + bb;
          h = scale_eff[bi * 64 + c] * h + shift[bi * 64 + c];
          float z = h * s2v + o2v;
          out_bf[(size_t)n * 64 + c] = f2bf(silu_f(z));
        }
      }
    }
  } else {
#pragma unroll
    for (int s = 0; s < 2; ++s) {
      f32x16 a = s ? acc1 : acc0;
      const int c = cb * 32 + r32;
      float bb = bias[c];
#pragma unroll
      for (int r = 0; r < 16; ++r) {
        int rowD = (r & 3) + 8 * (r >> 2) + 4 * half;
        int n = n0 + RH * 64 + s * 32 + rowD;
        if (n < N) {
          out_f[(size_t)n * 64 + c] = a[r] + bb + xres[(size_t)n * 64 + c];
        }
      }
    }
  }
}

extern "C" void kernel_launch(void* const* d_in, const int* in_sizes, int n_in,
                              void* d_out, int out_size, void* d_ws, size_t ws_size,
                              hipStream_t stream) {
  const float* x    = (const float*)d_in[0];
  const float* t    = (const float*)d_in[1];
  const int*   b    = (const int*)d_in[2];
  const int*   kidx = (const int*)d_in[3];
  const int*   kval = (const int*)d_in[4];
  const float* bn1g = (const float*)d_in[5];
  const float* bn1b = (const float*)d_in[6];
  const float* bn1m = (const float*)d_in[7];
  const float* bn1v = (const float*)d_in[8];
  const float* W1   = (const float*)d_in[9];
  const float* b1c  = (const float*)d_in[10];
  const float* bn2g = (const float*)d_in[11];
  const float* bn2b = (const float*)d_in[12];
  const float* bn2m = (const float*)d_in[13];
  const float* bn2v = (const float*)d_in[14];
  const float* W2   = (const float*)d_in[15];
  const float* b2c  = (const float*)d_in[16];
  const float* Wt   = (const float*)d_in[17];
  const float* bt   = (const float*)d_in[18];
  float* out = (float*)d_out;

  const int N = in_sizes[2];        // 100000
  const int total = N * 64;

  // workspace layout (bytes); act buffers have N+1 rows (row N = zeros)
  char* ws = (char*)d_ws;
  size_t actB = ((size_t)(N + 1) * 64 * 2 + 255) & ~(size_t)255;
  unsigned short* a1bf = (unsigned short*)ws;
  unsigned short* a2bf = (unsigned short*)(ws + actB);
  const size_t wpackB = (size_t)KOFF * 4 * 2 * 64 * 8 * 2;  // 221184 B
  unsigned short* W1p = (unsigned short*)(ws + 2 * actB);
  unsigned short* W2p = (unsigned short*)(ws + 2 * actB + wpackB);
  float* scale_eff = (float*)(ws + 2 * actB + 2 * wpackB);
  float* shiftp    = scale_eff + 16 * 64;

  time_mlp<<<8, 256, 0, stream>>>(t, Wt, bt, scale_eff, shiftp);
  const int wtot = KOFF * 4 * 2 * 64 * 8;
  pack_w32<<<(2 * wtot + 255) / 256, 256, 0, stream>>>(W1, W2, W1p, W2p);
  bn_silu_k<<<(total / 4 + 16 + 255) / 256, 256, 0, stream>>>(x, bn1g, bn1b, bn1m,
                                                              bn1v, a1bf, total);

  int nblk = (N + 127) / 128;
  conv_k<0><<<nblk, 256, 0, stream>>>(a1bf, kidx, kval, W1p, b1c, scale_eff,
                                      shiftp, b, bn2g, bn2b, bn2m, bn2v,
                                      nullptr, a2bf, nullptr, N);
  conv_k<1><<<nblk, 256, 0, stream>>>(a2bf, kidx, kval, W2p, b2c, nullptr, nullptr,
                                      nullptr, nullptr, nullptr, nullptr, nullptr,
                                      x, nullptr, out, N);
}

// Round 7
// 143.363 us; speedup vs baseline: 1.3735x; 1.0042x over previous
//
#include <hip/hip_runtime.h>

typedef __attribute__((ext_vector_type(8))) short short8;
typedef __attribute__((ext_vector_type(16))) float f32x16;
typedef __attribute__((ext_vector_type(4))) unsigned short ushort4v;

#define BN_EPS 1e-5f
#define KOFF 27

static __device__ __forceinline__ unsigned short f2bf(float f) {
  unsigned int u = __float_as_uint(f);
  u += 0x7fffu + ((u >> 16) & 1u);
  return (unsigned short)(u >> 16);
}

static __device__ __forceinline__ float silu_f(float z) {
  return z / (1.f + __expf(-z));
}

static __device__ __forceinline__ void gload_lds16(const void* g, void* l) {
  __builtin_amdgcn_global_load_lds(
      (const __attribute__((address_space(1))) unsigned int*)g,
      (__attribute__((address_space(3))) unsigned int*)l, 16, 0, 0);
}

// ---- time embedding MLP: tp = silu(t) @ Wt + bt; store (1+scale), shift
__global__ void time_mlp(const float* __restrict__ t, const float* __restrict__ Wt,
                         const float* __restrict__ bt,
                         float* __restrict__ scale_eff, float* __restrict__ shift) {
  int tid = blockIdx.x * blockDim.x + threadIdx.x; // 2048 = 16 batches * 128 out
  int bi = tid >> 7, co = tid & 127;
  float acc = bt[co];
  for (int e = 0; e < 256; ++e) {
    float tv = t[bi * 256 + e];
    acc += silu_f(tv) * Wt[e * 128 + co];
  }
  if (co < 64) scale_eff[bi * 64 + co] = 1.f + acc;
  else         shift[bi * 64 + (co - 64)] = acc;
}

// ---- pack W1 and W2 [k, ci, co] (f32) into bf16 MFMA B-fragment order (32x32x16).
// Fragment f = k*8 + ks*2 + cb : lane l elem j <- W[k][ks*16 + (l>>5)*8 + j][cb*32 + (l&31)]
__global__ void pack_w32(const float* __restrict__ W1, const float* __restrict__ W2,
                         unsigned short* __restrict__ Wp1, unsigned short* __restrict__ Wp2) {
  const int tot = KOFF * 4 * 2 * 64 * 8;
  int tid = blockIdx.x * blockDim.x + threadIdx.x;
  const float* W = W1;
  unsigned short* Wp = Wp1;
  if (tid >= tot) { tid -= tot; W = W2; Wp = Wp2; }
  if (tid >= tot) return;
  int j = tid & 7, lane = (tid >> 3) & 63, cb = (tid >> 9) & 1, ks = (tid >> 10) & 3, k = tid >> 12;
  int ci = ks * 16 + (lane >> 5) * 8 + j;
  int co = cb * 32 + (lane & 31);
  Wp[tid] = f2bf(W[(k * 64 + ci) * 64 + co]);
}

// ---- a1 = bf16(silu(bn1(x))), bn1 affine computed inline; tail threads zero row N
__global__ void bn_silu_k(const float* __restrict__ x, const float* __restrict__ g1,
                          const float* __restrict__ b1, const float* __restrict__ m1,
                          const float* __restrict__ v1, unsigned short* __restrict__ out,
                          int total) {
  int i = (blockIdx.x * blockDim.x + threadIdx.x) * 4;
  if (i >= total) {
    if (i < total + 64) *(ushort4v*)(out + i) = (ushort4v){0, 0, 0, 0};
    return;
  }
  float4 v = *(const float4*)(x + i);
  int c = i & 63;
  float4 g = *(const float4*)(g1 + c);
  float4 b = *(const float4*)(b1 + c);
  float4 m = *(const float4*)(m1 + c);
  float4 vv = *(const float4*)(v1 + c);
  ushort4v r;
  float sx = g.x * rsqrtf(vv.x + BN_EPS);
  float sy = g.y * rsqrtf(vv.y + BN_EPS);
  float sz = g.z * rsqrtf(vv.z + BN_EPS);
  float sw = g.w * rsqrtf(vv.w + BN_EPS);
  r.x = f2bf(silu_f((v.x - m.x) * sx + b.x));
  r.y = f2bf(silu_f((v.y - m.y) * sy + b.y));
  r.z = f2bf(silu_f((v.z - m.z) * sz + b.z));
  r.w = f2bf(silu_f((v.w - m.w) * sw + b.w));
  *(ushort4v*)(out + i) = r;
}

// ---- sparse conv with LDS-staged gather + W register double-buffer.
// Block = 256 threads / 4 waves / 128 nodes. Per tap: block's 128 gathered rows
// (16 KB) staged via global_load_lds (8 lanes x 16 B per row), double-buffered.
// XOR swizzle (chunk ^= row&7) applied on the GLOBAL SRC side (LDS dest linear).
// W fragments prefetched one tap ahead into registers (wreg), so COMPUTE(k) never
// waits on tap k+1's gathers (vmcnt FIFO ordering: everything older than wreg[k]
// already drained at the barrier ending iter k-1).
// Parity: rgA/wregA/buf0 = even taps, rgB/wregB/buf1 = odd taps.
//   iter k: STAGE(k+1) ; LDVG(k+2) ; Wload(k+1) ; COMPUTE(k) ; barrier
// Wave w: rows (w>>1)*64..+63 (2 sub-tiles of 32), cols (w&1)*32..+31.
// MODE 0: epilogue = +bias, FiLM, bn2+silu -> bf16 a2 (block 0 zeroes a2 row N)
// MODE 1: epilogue = +bias + residual x -> f32 out
template <int MODE>
__global__ __launch_bounds__(256, 3) void conv_k(
    const unsigned short* __restrict__ act, const int* __restrict__ idx,
    const int* __restrict__ valid, const unsigned short* __restrict__ Wp,
    const float* __restrict__ bias,
    const float* __restrict__ scale_eff, const float* __restrict__ shift,
    const int* __restrict__ bidx,
    const float* __restrict__ g2, const float* __restrict__ b2,
    const float* __restrict__ m2, const float* __restrict__ v2,
    const float* __restrict__ xres,
    unsigned short* __restrict__ out_bf, float* __restrict__ out_f, int N) {
  __shared__ unsigned short lds[2][128 * 64];

  if (MODE == 0 && blockIdx.x == 0 && threadIdx.x < 64) {
    out_bf[(size_t)N * 64 + threadIdx.x] = 0;  // zero row for conv2's invalid taps
  }
  const int tid = threadIdx.x;
  const int lane = tid & 63;
  const int wid = tid >> 6;
  const int half = lane >> 5;   // 0/1
  const int r32 = lane & 31;
  const int n0 = blockIdx.x * 128;

  // staging role: lane stages rows rowL = wid*32 + i*8 + (lane>>3), phys chunk lane&7
  const int rowL0 = wid * 32 + (lane >> 3);
  const int q0 = lane & 7;
  // compute role
  const int RH = wid >> 1;
  const int cb = wid & 1;

  f32x16 acc0, acc1;
#pragma unroll
  for (int i = 0; i < 16; ++i) { acc0[i] = 0.f; acc1[i] = 0.f; }

  int rgA[4], rgB[4];       // rgA: even taps, rgB: odd taps
  short8 wrA[4], wrB[4];    // W fragments, same parity

#define LDVG(kk, rg) do { \
    _Pragma("unroll") \
    for (int i = 0; i < 4; ++i) { \
      int node = min(n0 + rowL0 + i * 8, N - 1); \
      int v = valid[(size_t)(kk) * N + node]; \
      int g = idx[(size_t)(kk) * N + node]; \
      rg[i] = v ? g : N; \
    } } while (0)

  // LDS dest base is wave-uniform; HW adds lane*16. Lane's 16B lands at
  // row (wid*32+i*8+(lane>>3)), phys chunk (lane&7) -> row-major linear.
  // Source chunk pre-swizzled: srcq = (lane&7) ^ (row&7) = q0 ^ (lane>>3).
#define STAGE(buf, rg) do { \
    _Pragma("unroll") \
    for (int i = 0; i < 4; ++i) { \
      int srcq = q0 ^ (lane >> 3); \
      const unsigned short* src = act + (size_t)rg[i] * 64 + srcq * 8; \
      unsigned short* dst = &lds[buf][(wid * 32 + i * 8) * 64]; \
      gload_lds16(src, dst); \
    } } while (0)

#define WLOAD(kk, wr) do { \
    _Pragma("unroll") \
    for (int ks = 0; ks < 4; ++ks) \
      wr[ks] = ((const short8*)Wp)[((size_t)(kk) * 8 + ks * 2 + cb) * 64 + lane]; \
  } while (0)

  // fragment reads: logical chunk q = ks*2 + half of row R; phys p = q ^ (R&7); R&7 == r32&7
#define COMPUTE(buf, wr) do { \
    _Pragma("unroll") \
    for (int ks = 0; ks < 4; ++ks) { \
      int p = (ks * 2 + half) ^ (r32 & 7); \
      short8 a0v = *(const short8*)(&lds[buf][(RH * 64 + r32) * 64] + p * 8); \
      short8 a1v = *(const short8*)(&lds[buf][(RH * 64 + 32 + r32) * 64] + p * 8); \
      acc0 = __builtin_amdgcn_mfma_f32_32x32x16_bf16(a0v, wr[ks], acc0, 0, 0, 0); \
      acc1 = __builtin_amdgcn_mfma_f32_32x32x16_bf16(a1v, wr[ks], acc1, 0, 0, 0); \
    } } while (0)

  LDVG(0, rgA);        // tap 0 (even) -> rgA
  STAGE(0, rgA);       // buf0 <- tap 0
  LDVG(1, rgB);        // tap 1 (odd) -> rgB
  WLOAD(0, wrA);       // W for tap 0
  __syncthreads();     // implicit vmcnt(0): buf0 staged, wrA landed

#pragma unroll
  for (int k = 0; k < KOFF; ++k) {
    if (k + 1 < KOFF) {
      if ((k + 1) & 1) STAGE((k + 1) & 1, rgB);
      else             STAGE((k + 1) & 1, rgA);
    }
    if (k + 2 < KOFF) {
      if (k & 1) LDVG(k + 2, rgB);
      else       LDVG(k + 2, rgA);
    }
    if (k + 1 < KOFF) {
      if ((k + 1) & 1) WLOAD(k + 1, wrB);
      else             WLOAD(k + 1, wrA);
    }
    if (k & 1) COMPUTE(1, wrB);
    else       COMPUTE(0, wrA);
    __syncthreads();  // drains STAGE(k+1)/LDVG(k+2)/WLOAD(k+1); frees buf k
  }
#undef LDVG
#undef STAGE
#undef WLOAD
#undef COMPUTE

  // D frag: col = cb*32 + r32, row-in-subtile = (r&3) + 8*(r>>2) + 4*half
  if (MODE == 0) {
#pragma unroll
    for (int s = 0; s < 2; ++s) {
      f32x16 a = s ? acc1 : acc0;
      const int c = cb * 32 + r32;
      float bb = bias[c];
      float s2v = g2[c] * rsqrtf(v2[c] + BN_EPS);
      float o2v = b2[c] - m2[c] * s2v;
#pragma unroll
      for (int r = 0; r < 16; ++r) {
        int rowD = (r & 3) + 8 * (r >> 2) + 4 * half;
        int n = n0 + RH * 64 + s * 32 + rowD;
        if (n < N) {
          int bi = bidx[n];
          float h = a[r] + bb;
          h = scale_eff[bi * 64 + c] * h + shift[bi * 64 + c];
          float z = h * s2v + o2v;
          out_bf[(size_t)n * 64 + c] = f2bf(silu_f(z));
        }
      }
    }
  } else {
#pragma unroll
    for (int s = 0; s < 2; ++s) {
      f32x16 a = s ? acc1 : acc0;
      const int c = cb * 32 + r32;
      float bb = bias[c];
#pragma unroll
      for (int r = 0; r < 16; ++r) {
        int rowD = (r & 3) + 8 * (r >> 2) + 4 * half;
        int n = n0 + RH * 64 + s * 32 + rowD;
        if (n < N) {
          out_f[(size_t)n * 64 + c] = a[r] + bb + xres[(size_t)n * 64 + c];
        }
      }
    }
  }
}

extern "C" void kernel_launch(void* const* d_in, const int* in_sizes, int n_in,
                              void* d_out, int out_size, void* d_ws, size_t ws_size,
                              hipStream_t stream) {
  const float* x    = (const float*)d_in[0];
  const float* t    = (const float*)d_in[1];
  const int*   b    = (const int*)d_in[2];
  const int*   kidx = (const int*)d_in[3];
  const int*   kval = (const int*)d_in[4];
  const float* bn1g = (const float*)d_in[5];
  const float* bn1b = (const float*)d_in[6];
  const float* bn1m = (const float*)d_in[7];
  const float* bn1v = (const float*)d_in[8];
  const float* W1   = (const float*)d_in[9];
  const float* b1c  = (const float*)d_in[10];
  const float* bn2g = (const float*)d_in[11];
  const float* bn2b = (const float*)d_in[12];
  const float* bn2m = (const float*)d_in[13];
  const float* bn2v = (const float*)d_in[14];
  const float* W2   = (const float*)d_in[15];
  const float* b2c  = (const float*)d_in[16];
  const float* Wt   = (const float*)d_in[17];
  const float* bt   = (const float*)d_in[18];
  float* out = (float*)d_out;

  const int N = in_sizes[2];        // 100000
  const int total = N * 64;

  // workspace layout (bytes); act buffers have N+1 rows (row N = zeros)
  char* ws = (char*)d_ws;
  size_t actB = ((size_t)(N + 1) * 64 * 2 + 255) & ~(size_t)255;
  unsigned short* a1bf = (unsigned short*)ws;
  unsigned short* a2bf = (unsigned short*)(ws + actB);
  const size_t wpackB = (size_t)KOFF * 4 * 2 * 64 * 8 * 2;  // 221184 B
  unsigned short* W1p = (unsigned short*)(ws + 2 * actB);
  unsigned short* W2p = (unsigned short*)(ws + 2 * actB + wpackB);
  float* scale_eff = (float*)(ws + 2 * actB + 2 * wpackB);
  float* shiftp    = scale_eff + 16 * 64;

  time_mlp<<<8, 256, 0, stream>>>(t, Wt, bt, scale_eff, shiftp);
  const int wtot = KOFF * 4 * 2 * 64 * 8;
  pack_w32<<<(2 * wtot + 255) / 256, 256, 0, stream>>>(W1, W2, W1p, W2p);
  bn_silu_k<<<(total / 4 + 16 + 255) / 256, 256, 0, stream>>>(x, bn1g, bn1b, bn1m,
                                                              bn1v, a1bf, total);

  int nblk = (N + 127) / 128;
  conv_k<0><<<nblk, 256, 0, stream>>>(a1bf, kidx, kval, W1p, b1c, scale_eff,
                                      shiftp, b, bn2g, bn2b, bn2m, bn2v,
                                      nullptr, a2bf, nullptr, N);
  conv_k<1><<<nblk, 256, 0, stream>>>(a2bf, kidx, kval, W2p, b2c, nullptr, nullptr,
                                      nullptr, nullptr, nullptr, nullptr, nullptr,
                                      x, nullptr, out, N);
}